// Round 11
// baseline (2230.409 us; speedup 1.0000x reference)
//
#include <hip/hip_runtime.h>
#include <hip/hip_fp16.h>
#include <math.h>

#define DIM 128
#define HID 256
#define TSHIFT 14                 // src-tile = 16384 nodes = 2 MB fp8 rows
#define KMAX 7                    // max nodes per slot (n <= 114688 with 16384 slots)

typedef _Float16 f16;
typedef f16 f16x8 __attribute__((ext_vector_type(8)));
typedef float f32x4 __attribute__((ext_vector_type(4)));
typedef float f32x2 __attribute__((ext_vector_type(2)));

__device__ __forceinline__ float gelu_exact(float x) {
    return 0.5f * x * (1.0f + erff(x * 0.70710678118654752f));
}
__device__ __forceinline__ float2 h2f2(unsigned u) {
    __half2 h;
    *reinterpret_cast<unsigned*>(&h) = u;
    return __half22float2(h);
}
__device__ __forceinline__ unsigned f2h2(float a, float b) {
    __half2 h = __floats2half2_rn(a, b);
    return *reinterpret_cast<unsigned*>(&h);
}
// fp8 e4m3 (OCP on gfx950) pack/unpack via HW converts
__device__ __forceinline__ unsigned fp8pk4(float a, float b, float c, float d) {
    unsigned r = (unsigned)__builtin_amdgcn_cvt_pk_fp8_f32(a, b, 0, false);
    r = (unsigned)__builtin_amdgcn_cvt_pk_fp8_f32(c, d, (int)r, true);
    return r;
}

// ---------------- bucket count: deg2[tile(src)*n + dst] ----------------
__global__ __launch_bounds__(256) void k_deg2(const int* __restrict__ src, const int* __restrict__ dst,
                                              int* __restrict__ deg2, int E, int n) {
    int e = blockIdx.x * 256 + threadIdx.x;
    if (e >= E) return;
    int s = src[e], d = dst[e];
    atomicAdd(&deg2[(s >> TSHIFT) * n + d], 1);
}

// ---------------- per-node scales from bucket offsets ----------------
__global__ __launch_bounds__(256) void k_dscale(const int* __restrict__ offs2, float* __restrict__ invdeg,
                                                float* __restrict__ sqdeg, float* __restrict__ rsq,
                                                int n, int nt) {
    int v = blockIdx.x * 256 + threadIdx.x;
    if (v >= n) return;
    int deg = 0;
    for (int t = 0; t < nt; ++t) deg += offs2[t * n + v + 1] - offs2[t * n + v];
    float d = (float)deg;
    invdeg[v] = 1.0f / d;
    sqdeg[v] = sqrtf(d);
    rsq[v] = rsqrtf(d);
}

// ---------------- prefix-sum (generic over n2 elements) ----------------
__global__ __launch_bounds__(256) void k_scan_part(const int* __restrict__ deg, int* __restrict__ bsum, int n) {
    __shared__ int sred[256];
    int base = blockIdx.x * 1024 + threadIdx.x * 4;
    int s = 0;
#pragma unroll
    for (int k = 0; k < 4; ++k) { int i = base + k; if (i < n) s += deg[i]; }
    sred[threadIdx.x] = s; __syncthreads();
    for (int st = 128; st > 0; st >>= 1) {
        if (threadIdx.x < st) sred[threadIdx.x] += sred[threadIdx.x + st];
        __syncthreads();
    }
    if (threadIdx.x == 0) bsum[blockIdx.x] = sred[0];
}

__global__ void k_scan_bsum(int* bsum, int nb, int* offs, int n, int E) {
    if (threadIdx.x == 0 && blockIdx.x == 0) {
        int run = 0;
        for (int b = 0; b < nb; ++b) { int t = bsum[b]; bsum[b] = run; run += t; }
        offs[n] = E;
    }
}

__global__ __launch_bounds__(256) void k_scan_off(const int* __restrict__ deg, const int* __restrict__ bsum,
                                                  int* __restrict__ offs, int n) {
    __shared__ int sps[256];
    int tid = threadIdx.x;
    int base = blockIdx.x * 1024 + tid * 4;
    int v[4]; int s = 0;
#pragma unroll
    for (int k = 0; k < 4; ++k) { int i = base + k; v[k] = (i < n) ? deg[i] : 0; s += v[k]; }
    sps[tid] = s; __syncthreads();
    for (int st = 1; st < 256; st <<= 1) {
        int add = (tid >= st) ? sps[tid - st] : 0;
        __syncthreads();
        sps[tid] += add;
        __syncthreads();
    }
    int run = sps[tid] - s + bsum[blockIdx.x];
#pragma unroll
    for (int k = 0; k < 4; ++k) { int i = base + k; if (i < n) offs[i] = run; run += v[k]; }
}

// ---------------- bucketed CSR fill: edges grouped (src-tile major, dst minor) ----------------
__global__ __launch_bounds__(256) void k_fill(const int* __restrict__ src, const int* __restrict__ dst,
                                              const int* __restrict__ offs2, int* __restrict__ cursor2,
                                              unsigned* __restrict__ cedge, int E, int n) {
    int e = blockIdx.x * 256 + threadIdx.x;
    if (e >= E) return;
    int s = src[e], d = dst[e];
    int idx = (s >> TSHIFT) * n + d;
    int pos = offs2[idx] + atomicAdd(&cursor2[idx], 1);
    cedge[pos] = (unsigned)s;
}

// ---------------- bundle transform: g0 = (R @ X) * rsq, fp8 out ----------------
__global__ __launch_bounds__(256) void k_bundle(const float* __restrict__ x, const float* __restrict__ nr,
                                                const float* __restrict__ rsq, unsigned char* __restrict__ h, int n) {
    int t = blockIdx.x * 256 + threadIdx.x;
    if (t >= n * 8) return;
    int node = t >> 3, b = t & 7;
    float rs = rsq[node];
    const float4* Xp = (const float4*)(x + (size_t)node * DIM + b * 16);
    const float4* Rp = (const float4*)(nr + (size_t)node * DIM + b * 16);
    float4 X[4], R[4];
#pragma unroll
    for (int k = 0; k < 4; ++k) { X[k] = Xp[k]; R[k] = Rp[k]; }
    unsigned o[4];
#pragma unroll
    for (int c = 0; c < 4; ++c) {
        float4 Rc = R[c];
        float4 O;
        O.x = fmaf(Rc.x, X[0].x, fmaf(Rc.y, X[1].x, fmaf(Rc.z, X[2].x, Rc.w * X[3].x)));
        O.y = fmaf(Rc.x, X[0].y, fmaf(Rc.y, X[1].y, fmaf(Rc.z, X[2].y, Rc.w * X[3].y)));
        O.z = fmaf(Rc.x, X[0].z, fmaf(Rc.y, X[1].z, fmaf(Rc.z, X[2].z, Rc.w * X[3].z)));
        O.w = fmaf(Rc.x, X[0].w, fmaf(Rc.y, X[1].w, fmaf(Rc.z, X[2].w, Rc.w * X[3].w)));
        o[c] = fp8pk4(O.x * rs, O.y * rs, O.z * rs, O.w * rs);
    }
    *(uint4*)(h + (size_t)node * DIM + b * 16) = make_uint4(o[0], o[1], o[2], o[3]);
}

// ---------------- softmax over 5 attention weights ----------------
__global__ void k_softmax(const float* __restrict__ a, float* __restrict__ att) {
    if (threadIdx.x != 0 || blockIdx.x != 0) return;
    float m = a[0];
    for (int i = 1; i < 5; ++i) m = fmaxf(m, a[i]);
    float e[5], ssum = 0.f;
    for (int i = 0; i < 5; ++i) { e[i] = expf(a[i] - m); ssum += e[i]; }
    for (int i = 0; i < 5; ++i) att[i] = e[i] / ssum;
}

// ---------------- W -> fp16, transposed for MFMA B-fragments ----------------
__global__ __launch_bounds__(256) void k_wcvt(const float* __restrict__ W1, const float* __restrict__ W2,
                                              f16* __restrict__ W1T, f16* __restrict__ W2T) {
    int t = blockIdx.x * 256 + threadIdx.x;
    if (t < DIM * HID) {
        int k = t >> 8, j = t & 255;
        W1T[(size_t)j * DIM + k] = (f16)W1[(size_t)k * HID + j];
        int j2 = t >> 7, i = t & 127;
        W2T[(size_t)i * HID + j2] = (f16)W2[(size_t)j2 * DIM + i];
    }
}

// ---------------- propagation, SRC-TILED persistent grid ----------------
// 1024 blocks x 256 thr (4/CU, co-resident). 16-lane group = slot; each slot owns KMAX nodes
// (v = slot + k*16384) with fp32 accumulators in registers. Outer loop over src-tiles:
// entire GPU gathers from one 2 MB tile window at a time -> tile lives in every XCD L2.
__device__ __forceinline__ void acc8f8(float* f, uint2 h) {
    f32x2 p0 = __builtin_amdgcn_cvt_pk_f32_fp8(h.x, false);
    f32x2 p1 = __builtin_amdgcn_cvt_pk_f32_fp8(h.x, true);
    f32x2 p2 = __builtin_amdgcn_cvt_pk_f32_fp8(h.y, false);
    f32x2 p3 = __builtin_amdgcn_cvt_pk_f32_fp8(h.y, true);
    f[0] += p0.x; f[1] += p0.y; f[2] += p1.x; f[3] += p1.y;
    f[4] += p2.x; f[5] += p2.y; f[6] += p3.x; f[7] += p3.y;
}

__global__ __launch_bounds__(256, 4) void k_prop(const uint2* __restrict__ hin, uint2* __restrict__ hout,
                                                 const int* __restrict__ offs2, const unsigned* __restrict__ cedge,
                                                 const float* __restrict__ invdeg, int n, int nt) {
    int slot = blockIdx.x * 16 + (threadIdx.x >> 4);   // 0..16383
    int lane = threadIdx.x & 15;
    int nslots = gridDim.x * 16;                       // 16384
    const uint2* hb = hin + lane;                      // + s*16 = row s (128 B)
    float acc[KMAX][8];
#pragma unroll
    for (int k = 0; k < KMAX; ++k)
#pragma unroll
        for (int j = 0; j < 8; ++j) acc[k][j] = 0.f;

    for (int t = 0; t < nt; ++t) {
        const int* ob = offs2 + (size_t)t * n;
#pragma unroll
        for (int k = 0; k < KMAX; ++k) {
            int v = slot + k * nslots;
            if (v < n) {
                int b = ob[v], e = ob[v + 1];
                int i = b;
                for (; i + 2 <= e; i += 2) {
                    unsigned e0 = cedge[i], e1 = cedge[i + 1];
                    uint2 h0 = hb[(size_t)e0 * 16];
                    uint2 h1 = hb[(size_t)e1 * 16];
                    acc8f8(acc[k], h0);
                    acc8f8(acc[k], h1);
                }
                if (i < e) {
                    uint2 h0 = hb[(size_t)cedge[i] * 16];
                    acc8f8(acc[k], h0);
                }
            }
        }
    }
#pragma unroll
    for (int k = 0; k < KMAX; ++k) {
        int v = slot + k * nslots;
        if (v < n) {
            float idv = invdeg[v];
            uint2 ov;
            ov.x = fp8pk4(acc[k][0] * idv, acc[k][1] * idv, acc[k][2] * idv, acc[k][3] * idv);
            ov.y = fp8pk4(acc[k][4] * idv, acc[k][5] * idv, acc[k][6] * idv, acc[k][7] * idv);
            hout[(size_t)v * 16 + lane] = ov;
        }
    }
}

// ---------------- FFN via MFMA: gelu((sqdeg * Σ att_k S_k)@W1+b1)@W2+b2, fp16 out ----------------
#define SA_LD 136   // 64x136 fp16: 272B row stride (17x16B) -> aligned, 2-way bank alias (free)
#define SH_LD 264   // 64x264 fp16: 528B row stride (33x16B) -> aligned
__global__ __launch_bounds__(256, 3) void k_ffn_mfma(const unsigned char* __restrict__ S0,
                                                     const unsigned char* __restrict__ S1,
                                                     const unsigned char* __restrict__ S2,
                                                     const unsigned char* __restrict__ S3,
                                                     const float* __restrict__ attv, const float* __restrict__ sqdeg,
                                                     const f16* __restrict__ W1T, const float* __restrict__ b1,
                                                     const f16* __restrict__ W2T, const float* __restrict__ b2,
                                                     __half* __restrict__ outb, int n) {
    __shared__ f16 sA[64 * SA_LD];
    __shared__ f16 sH[64 * SH_LD];
    int tid = threadIdx.x;
    int wid = tid >> 6;
    int lane = tid & 63;
    int row16 = lane & 15;
    int kgrp = lane >> 4;     // 0..3
    int r0 = blockIdx.x * 64;
    float a0 = attv[0], a1 = attv[1], a2 = attv[2], a3 = attv[3];

    // stage sA: row = sqdeg[row] * (a0*S0 + a1*S1 + a2*S2 + a3*S3), fp8 -> fp16
    const uint2* p0 = (const uint2*)S0;
    const uint2* p1 = (const uint2*)S1;
    const uint2* p2 = (const uint2*)S2;
    const uint2* p3 = (const uint2*)S3;
    for (int idx = tid; idx < 64 * 16; idx += 256) {
        int r = idx >> 4;
        int ch = idx & 15;                 // 8-B chunk (8 fp8 values)
        int row = r0 + r; row = (row < n) ? row : (n - 1);
        float sd = sqdeg[row];
        float w0 = a0 * sd, w1 = a1 * sd, w2 = a2 * sd, w3 = a3 * sd;
        size_t u = (size_t)row * 16 + ch;
        uint2 x0 = p0[u], x1 = p1[u], x2 = p2[u], x3 = p3[u];
        float rv[8];
#pragma unroll
        for (int half = 0; half < 2; ++half) {
            unsigned q0 = half ? x0.y : x0.x, q1 = half ? x1.y : x1.x;
            unsigned q2 = half ? x2.y : x2.x, q3 = half ? x3.y : x3.x;
            f32x2 d0l = __builtin_amdgcn_cvt_pk_f32_fp8(q0, false);
            f32x2 d0h = __builtin_amdgcn_cvt_pk_f32_fp8(q0, true);
            f32x2 d1l = __builtin_amdgcn_cvt_pk_f32_fp8(q1, false);
            f32x2 d1h = __builtin_amdgcn_cvt_pk_f32_fp8(q1, true);
            f32x2 d2l = __builtin_amdgcn_cvt_pk_f32_fp8(q2, false);
            f32x2 d2h = __builtin_amdgcn_cvt_pk_f32_fp8(q2, true);
            f32x2 d3l = __builtin_amdgcn_cvt_pk_f32_fp8(q3, false);
            f32x2 d3h = __builtin_amdgcn_cvt_pk_f32_fp8(q3, true);
            rv[half * 4 + 0] = w0 * d0l.x + w1 * d1l.x + w2 * d2l.x + w3 * d3l.x;
            rv[half * 4 + 1] = w0 * d0l.y + w1 * d1l.y + w2 * d2l.y + w3 * d3l.y;
            rv[half * 4 + 2] = w0 * d0h.x + w1 * d1h.x + w2 * d2h.x + w3 * d3h.x;
            rv[half * 4 + 3] = w0 * d0h.y + w1 * d1h.y + w2 * d2h.y + w3 * d3h.y;
        }
        *(uint4*)(&sA[r * SA_LD + ch * 8]) = make_uint4(f2h2(rv[0], rv[1]), f2h2(rv[2], rv[3]),
                                                        f2h2(rv[4], rv[5]), f2h2(rv[6], rv[7]));
    }
    __syncthreads();

    // ---- GEMM1: sH[0:64][wid*64 : wid*64+64] = gelu(sA @ W1 + b1) ----
    {
        float bias1[4];
#pragma unroll
        for (int nt = 0; nt < 4; ++nt) bias1[nt] = b1[wid * 64 + nt * 16 + row16];
        f32x4 c1[4][4];
#pragma unroll
        for (int mt = 0; mt < 4; ++mt)
#pragma unroll
            for (int nt = 0; nt < 4; ++nt) c1[mt][nt] = (f32x4){0.f, 0.f, 0.f, 0.f};
        for (int ks = 0; ks < 4; ++ks) {   // K = 128 = 4 x 32
            f16x8 a[4], b[4];
#pragma unroll
            for (int mt = 0; mt < 4; ++mt)
                a[mt] = *(const f16x8*)(&sA[(mt * 16 + row16) * SA_LD + ks * 32 + kgrp * 8]);
#pragma unroll
            for (int nt = 0; nt < 4; ++nt)
                b[nt] = *(const f16x8*)(W1T + (size_t)(wid * 64 + nt * 16 + row16) * DIM + ks * 32 + kgrp * 8);
#pragma unroll
            for (int mt = 0; mt < 4; ++mt)
#pragma unroll
                for (int nt = 0; nt < 4; ++nt)
                    c1[mt][nt] = __builtin_amdgcn_mfma_f32_16x16x32_f16(a[mt], b[nt], c1[mt][nt], 0, 0, 0);
        }
#pragma unroll
        for (int mt = 0; mt < 4; ++mt)
#pragma unroll
            for (int nt = 0; nt < 4; ++nt) {
                int srow = mt * 16 + kgrp * 4;
                int scol = wid * 64 + nt * 16 + row16;
#pragma unroll
                for (int r = 0; r < 4; ++r) {
                    float v = c1[mt][nt][r] + bias1[nt];
                    sH[(srow + r) * SH_LD + scol] = (f16)gelu_exact(v);
                }
            }
    }
    __syncthreads();

    // ---- GEMM2: out[0:64][wid*32 : wid*32+32] = sH @ W2 + b2 (fp16 out) ----
    {
        float bias2[2];
#pragma unroll
        for (int nt = 0; nt < 2; ++nt) bias2[nt] = b2[wid * 32 + nt * 16 + row16];
        f32x4 c2[4][2];
#pragma unroll
        for (int mt = 0; mt < 4; ++mt)
#pragma unroll
            for (int nt = 0; nt < 2; ++nt) c2[mt][nt] = (f32x4){0.f, 0.f, 0.f, 0.f};
        for (int ks = 0; ks < 8; ++ks) {   // K = 256 = 8 x 32
            f16x8 a[4], b[2];
#pragma unroll
            for (int mt = 0; mt < 4; ++mt)
                a[mt] = *(const f16x8*)(&sH[(mt * 16 + row16) * SH_LD + ks * 32 + kgrp * 8]);
#pragma unroll
            for (int nt = 0; nt < 2; ++nt)
                b[nt] = *(const f16x8*)(W2T + (size_t)(wid * 32 + nt * 16 + row16) * HID + ks * 32 + kgrp * 8);
#pragma unroll
            for (int mt = 0; mt < 4; ++mt)
#pragma unroll
                for (int nt = 0; nt < 2; ++nt)
                    c2[mt][nt] = __builtin_amdgcn_mfma_f32_16x16x32_f16(a[mt], b[nt], c2[mt][nt], 0, 0, 0);
        }
#pragma unroll
        for (int mt = 0; mt < 4; ++mt)
#pragma unroll
            for (int nt = 0; nt < 2; ++nt) {
                int col = wid * 32 + nt * 16 + row16;
#pragma unroll
                for (int r = 0; r < 4; ++r) {
                    int row = r0 + mt * 16 + kgrp * 4 + r;
                    if (row < n) outb[(size_t)row * DIM + col] = (__half)(c2[mt][nt][r] + bias2[nt]);
                }
            }
    }
}

// ---------------- inverse bundle (R^T @ H), H fp16, + concat output ----------------
__global__ __launch_bounds__(256) void k_inv_out(const float* __restrict__ x, const float* __restrict__ nr,
                                                 const __half* __restrict__ hf, float* __restrict__ out, int n) {
    int t = blockIdx.x * 256 + threadIdx.x;
    if (t >= n * 8) return;
    int node = t >> 3, b = t & 7;
    const float4* Xin = (const float4*)(x + (size_t)node * DIM + b * 16);
    float4* Ox = (float4*)(out + (size_t)node * 2 * DIM + b * 16);
#pragma unroll
    for (int k = 0; k < 4; ++k) Ox[k] = Xin[k];
    const uint4* Hp = (const uint4*)(hf + (size_t)node * DIM + b * 16);
    uint4 hlo = Hp[0], hhi = Hp[1];
    float4 H[4];
    {
        float2 u0 = h2f2(hlo.x), u1 = h2f2(hlo.y);
        H[0] = make_float4(u0.x, u0.y, u1.x, u1.y);
        float2 u2 = h2f2(hlo.z), u3 = h2f2(hlo.w);
        H[1] = make_float4(u2.x, u2.y, u3.x, u3.y);
        float2 u4 = h2f2(hhi.x), u5 = h2f2(hhi.y);
        H[2] = make_float4(u4.x, u4.y, u5.x, u5.y);
        float2 u6 = h2f2(hhi.z), u7 = h2f2(hhi.w);
        H[3] = make_float4(u6.x, u6.y, u7.x, u7.y);
    }
    const float4* Rp = (const float4*)(nr + (size_t)node * DIM + b * 16);
    float4 R[4];
#pragma unroll
    for (int k = 0; k < 4; ++k) R[k] = Rp[k];
    float4* Om = (float4*)(out + (size_t)node * 2 * DIM + DIM + b * 16);
    {
        float4 O;
        O.x = fmaf(R[0].x, H[0].x, fmaf(R[1].x, H[1].x, fmaf(R[2].x, H[2].x, R[3].x * H[3].x)));
        O.y = fmaf(R[0].x, H[0].y, fmaf(R[1].x, H[1].y, fmaf(R[2].x, H[2].y, R[3].x * H[3].y)));
        O.z = fmaf(R[0].x, H[0].z, fmaf(R[1].x, H[1].z, fmaf(R[2].x, H[2].z, R[3].x * H[3].z)));
        O.w = fmaf(R[0].x, H[0].w, fmaf(R[1].x, H[1].w, fmaf(R[2].x, H[2].w, R[3].x * H[3].w)));
        Om[0] = O;
    }
    {
        float4 O;
        O.x = fmaf(R[0].y, H[0].x, fmaf(R[1].y, H[1].x, fmaf(R[2].y, H[2].x, R[3].y * H[3].x)));
        O.y = fmaf(R[0].y, H[0].y, fmaf(R[1].y, H[1].y, fmaf(R[2].y, H[2].y, R[3].y * H[3].y)));
        O.z = fmaf(R[0].y, H[0].z, fmaf(R[1].y, H[1].z, fmaf(R[2].y, H[2].z, R[3].y * H[3].z)));
        O.w = fmaf(R[0].y, H[0].w, fmaf(R[1].y, H[1].w, fmaf(R[2].y, H[2].w, R[3].y * H[3].w)));
        Om[1] = O;
    }
    {
        float4 O;
        O.x = fmaf(R[0].z, H[0].x, fmaf(R[1].z, H[1].x, fmaf(R[2].z, H[2].x, R[3].z * H[3].x)));
        O.y = fmaf(R[0].z, H[0].y, fmaf(R[1].z, H[1].y, fmaf(R[2].z, H[2].y, R[3].z * H[3].y)));
        O.z = fmaf(R[0].z, H[0].z, fmaf(R[1].z, H[1].z, fmaf(R[2].z, H[2].z, R[3].z * H[3].z)));
        O.w = fmaf(R[0].z, H[0].w, fmaf(R[1].z, H[1].w, fmaf(R[2].z, H[2].w, R[3].z * H[3].w)));
        Om[2] = O;
    }
    {
        float4 O;
        O.x = fmaf(R[0].w, H[0].x, fmaf(R[1].w, H[1].x, fmaf(R[2].w, H[2].x, R[3].w * H[3].x)));
        O.y = fmaf(R[0].w, H[0].y, fmaf(R[1].w, H[1].y, fmaf(R[2].w, H[2].y, R[3].w * H[3].y)));
        O.z = fmaf(R[0].w, H[0].z, fmaf(R[1].w, H[1].z, fmaf(R[2].w, H[2].z, R[3].w * H[3].z)));
        O.w = fmaf(R[0].w, H[0].w, fmaf(R[1].w, H[1].w, fmaf(R[2].w, H[2].w, R[3].w * H[3].w)));
        Om[3] = O;
    }
}

extern "C" void kernel_launch(void* const* d_in, const int* in_sizes, int n_in,
                              void* d_out, int out_size, void* d_ws, size_t ws_size,
                              hipStream_t stream) {
    const float* x         = (const float*)d_in[0];
    const float* nrep      = (const float*)d_in[1];
    const int*   src       = (const int*)d_in[2];
    const int*   dst       = (const int*)d_in[3];
    const float* attention = (const float*)d_in[4];
    const float* W1        = (const float*)d_in[5];
    const float* b1        = (const float*)d_in[6];
    const float* W2        = (const float*)d_in[7];
    const float* b2        = (const float*)d_in[8];
    float* out = (float*)d_out;

    int n = in_sizes[0] / DIM;
    int E = in_sizes[2];
    int NT = (n + (1 << TSHIFT) - 1) >> TSHIFT;   // 7 for n=100000
    int n2 = n * NT;

    char* w = (char*)d_ws;
    size_t off = 0;
    auto alloc = [&](size_t bytes) -> char* {
        char* p = w + off;
        off = (off + bytes + 255) & ~(size_t)255;
        return p;
    };
    size_t hbytes = (size_t)n * DIM;       // fp8 h buffer (1 B/elem)
    int*      deg2    = (int*)alloc((size_t)n2 * 4);
    int*      cursor2 = (int*)alloc((size_t)n2 * 4);
    int*      offs2   = (int*)alloc((size_t)(n2 + 1) * 4);
    int       nb2     = (n2 + 1023) / 1024;
    int*      bsum    = (int*)alloc((size_t)nb2 * 4);
    float*    attbuf  = (float*)alloc(8 * 4);
    float*    invdeg  = (float*)alloc((size_t)n * 4);
    float*    sqdeg   = (float*)alloc((size_t)n * 4);
    float*    rsq     = (float*)alloc((size_t)n * 4);
    unsigned* cedge   = (unsigned*)alloc((size_t)E * 4);
    char*     region  = alloc(hbytes * 2);         // B0 + T1 (fp8); ffin (fp16) overlays both
    unsigned char* B0 = (unsigned char*)region;
    unsigned char* T1 = (unsigned char*)(region + hbytes);
    __half*   ffin    = (__half*)region;           // n*DIM*2 bytes = hbytes*2
    unsigned char* S[4];
    for (int k = 0; k < 4; ++k) S[k] = (unsigned char*)alloc(hbytes);
    f16*      W1T     = (f16*)alloc((size_t)DIM * HID * 2);
    f16*      W2T     = (f16*)alloc((size_t)DIM * HID * 2);

    hipMemsetAsync(deg2, 0, (size_t)n2 * 4, stream);
    hipMemsetAsync(cursor2, 0, (size_t)n2 * 4, stream);

    k_deg2<<<(E + 255) / 256, 256, 0, stream>>>(src, dst, deg2, E, n);
    k_scan_part<<<nb2, 256, 0, stream>>>(deg2, bsum, n2);
    k_scan_bsum<<<1, 64, 0, stream>>>(bsum, nb2, offs2, n2, E);
    k_scan_off<<<nb2, 256, 0, stream>>>(deg2, bsum, offs2, n2);
    k_dscale<<<(n + 255) / 256, 256, 0, stream>>>(offs2, invdeg, sqdeg, rsq, n, NT);
    k_fill<<<(E + 255) / 256, 256, 0, stream>>>(src, dst, offs2, cursor2, cedge, E, n);
    k_bundle<<<(n * 8 + 255) / 256, 256, 0, stream>>>(x, nrep, rsq, B0, n);
    k_softmax<<<1, 64, 0, stream>>>(attention, attbuf);
    k_wcvt<<<(DIM * HID + 255) / 256, 256, 0, stream>>>(W1, W2, W1T, W2T);

    // snapshots at t = 1,2,5,20 land in S0..S3 by buffer scheduling (never overwritten after)
    unsigned char* cur = B0;
    for (int t = 1; t <= 20; ++t) {   // t=21 in reference is dead code
        int snap = (t == 1) ? 0 : (t == 2) ? 1 : (t == 5) ? 2 : (t == 20) ? 3 : -1;
        unsigned char* nxt = (snap >= 0) ? S[snap] : ((cur == B0) ? T1 : B0);
        k_prop<<<1024, 256, 0, stream>>>((const uint2*)cur, (uint2*)nxt, offs2, cedge, invdeg, n, NT);
        cur = nxt;
    }
    k_ffn_mfma<<<(n + 63) / 64, 256, 0, stream>>>(S[0], S[1], S[2], S[3], attbuf, sqdeg,
                                                  W1T, b1, W2T, b2, ffin, n);
    k_inv_out<<<(n * 8 + 255) / 256, 256, 0, stream>>>(x, nrep, ffin, out, n);
}

// Round 12
// 907.683 us; speedup vs baseline: 2.4573x; 2.4573x over previous
//
#include <hip/hip_runtime.h>
#include <hip/hip_fp16.h>
#include <math.h>

#define DIM 128
#define HID 256

typedef _Float16 f16;
typedef f16 f16x8 __attribute__((ext_vector_type(8)));
typedef float f32x4 __attribute__((ext_vector_type(4)));
typedef float f32x2 __attribute__((ext_vector_type(2)));

__device__ __forceinline__ float gelu_exact(float x) {
    return 0.5f * x * (1.0f + erff(x * 0.70710678118654752f));
}
__device__ __forceinline__ float2 h2f2(unsigned u) {
    __half2 h;
    *reinterpret_cast<unsigned*>(&h) = u;
    return __half22float2(h);
}
__device__ __forceinline__ unsigned f2h2(float a, float b) {
    __half2 h = __floats2half2_rn(a, b);
    return *reinterpret_cast<unsigned*>(&h);
}
// fp8 e4m3 (OCP on gfx950) pack/unpack via HW converts
__device__ __forceinline__ unsigned fp8pk4(float a, float b, float c, float d) {
    unsigned r = (unsigned)__builtin_amdgcn_cvt_pk_fp8_f32(a, b, 0, false);
    r = (unsigned)__builtin_amdgcn_cvt_pk_fp8_f32(c, d, (int)r, true);
    return r;
}

// ---------------- degree count ----------------
__global__ __launch_bounds__(256) void k_deg(const int* __restrict__ src, int* __restrict__ deg, int E) {
    int e = blockIdx.x * 256 + threadIdx.x;
    if (e < E) atomicAdd(&deg[src[e]], 1);
}

// ---------------- per-node scales ----------------
__global__ __launch_bounds__(256) void k_dscale(const int* __restrict__ deg, float* __restrict__ invdeg,
                                                float* __restrict__ sqdeg, int n) {
    int v = blockIdx.x * 256 + threadIdx.x;
    if (v >= n) return;
    float d = (float)deg[v];
    invdeg[v] = 1.0f / d;
    sqdeg[v] = sqrtf(d);
}

// ---------------- prefix-sum of degrees ----------------
__global__ __launch_bounds__(256) void k_scan_part(const int* __restrict__ deg, int* __restrict__ bsum, int n) {
    __shared__ int sred[256];
    int base = blockIdx.x * 1024 + threadIdx.x * 4;
    int s = 0;
#pragma unroll
    for (int k = 0; k < 4; ++k) { int i = base + k; if (i < n) s += deg[i]; }
    sred[threadIdx.x] = s; __syncthreads();
    for (int st = 128; st > 0; st >>= 1) {
        if (threadIdx.x < st) sred[threadIdx.x] += sred[threadIdx.x + st];
        __syncthreads();
    }
    if (threadIdx.x == 0) bsum[blockIdx.x] = sred[0];
}

__global__ void k_scan_bsum(int* bsum, int nb, int* offs, int n, int E) {
    if (threadIdx.x == 0 && blockIdx.x == 0) {
        int run = 0;
        for (int b = 0; b < nb; ++b) { int t = bsum[b]; bsum[b] = run; run += t; }
        offs[n] = E;
    }
}

__global__ __launch_bounds__(256) void k_scan_off(const int* __restrict__ deg, const int* __restrict__ bsum,
                                                  int* __restrict__ offs, int n) {
    __shared__ int sps[256];
    int tid = threadIdx.x;
    int base = blockIdx.x * 1024 + tid * 4;
    int v[4]; int s = 0;
#pragma unroll
    for (int k = 0; k < 4; ++k) { int i = base + k; v[k] = (i < n) ? deg[i] : 0; s += v[k]; }
    sps[tid] = s; __syncthreads();
    for (int st = 1; st < 256; st <<= 1) {
        int add = (tid >= st) ? sps[tid - st] : 0;
        __syncthreads();
        sps[tid] += add;
        __syncthreads();
    }
    int run = sps[tid] - s + bsum[blockIdx.x];
#pragma unroll
    for (int k = 0; k < 4; ++k) { int i = base + k; if (i < n) offs[i] = run; run += v[k]; }
}

// ---------------- CSR fill (by dst), XCD-PARTITIONED ----------------
#define FCHUNK 4096
__global__ __launch_bounds__(256) void k_fill(const int* __restrict__ src, const int* __restrict__ dst,
                                              const int* __restrict__ offs, int* __restrict__ cursor,
                                              unsigned* __restrict__ cedge, int E, int n) {
    int part = blockIdx.x & 7;
    int chunk = blockIdx.x >> 3;
    int per = (n + 7) >> 3;
    int lo = part * per;
    int hi = lo + per; hi = (hi < n) ? hi : n;
    int base = chunk * FCHUNK;
    int end = base + FCHUNK; end = (end < E) ? end : E;
    for (int e = base + threadIdx.x; e < end; e += 256) {
        int d = __builtin_nontemporal_load(dst + e);
        if (d >= lo && d < hi) {
            int s = __builtin_nontemporal_load(src + e);
            int pos = offs[d] + atomicAdd(&cursor[d], 1);
            cedge[pos] = (unsigned)s;
        }
    }
}

// ---------------- bundle transform: g0 = (R @ X) / sqrt(deg), fp8 out ----------------
__global__ __launch_bounds__(256) void k_bundle(const float* __restrict__ x, const float* __restrict__ nr,
                                                const int* __restrict__ deg, unsigned char* __restrict__ h, int n) {
    int t = blockIdx.x * 256 + threadIdx.x;
    if (t >= n * 8) return;
    int node = t >> 3, b = t & 7;
    float rs = rsqrtf((float)deg[node]);
    const float4* Xp = (const float4*)(x + (size_t)node * DIM + b * 16);
    const float4* Rp = (const float4*)(nr + (size_t)node * DIM + b * 16);
    float4 X[4], R[4];
#pragma unroll
    for (int k = 0; k < 4; ++k) { X[k] = Xp[k]; R[k] = Rp[k]; }
    unsigned o[4];
#pragma unroll
    for (int c = 0; c < 4; ++c) {
        float4 Rc = R[c];
        float4 O;
        O.x = fmaf(Rc.x, X[0].x, fmaf(Rc.y, X[1].x, fmaf(Rc.z, X[2].x, Rc.w * X[3].x)));
        O.y = fmaf(Rc.x, X[0].y, fmaf(Rc.y, X[1].y, fmaf(Rc.z, X[2].y, Rc.w * X[3].y)));
        O.z = fmaf(Rc.x, X[0].z, fmaf(Rc.y, X[1].z, fmaf(Rc.z, X[2].z, Rc.w * X[3].z)));
        O.w = fmaf(Rc.x, X[0].w, fmaf(Rc.y, X[1].w, fmaf(Rc.z, X[2].w, Rc.w * X[3].w)));
        o[c] = fp8pk4(O.x * rs, O.y * rs, O.z * rs, O.w * rs);
    }
    *(uint4*)(h + (size_t)node * DIM + b * 16) = make_uint4(o[0], o[1], o[2], o[3]);
}

// ---------------- softmax over 5 attention weights ----------------
__global__ void k_softmax(const float* __restrict__ a, float* __restrict__ att) {
    if (threadIdx.x != 0 || blockIdx.x != 0) return;
    float m = a[0];
    for (int i = 1; i < 5; ++i) m = fmaxf(m, a[i]);
    float e[5], ssum = 0.f;
    for (int i = 0; i < 5; ++i) { e[i] = expf(a[i] - m); ssum += e[i]; }
    for (int i = 0; i < 5; ++i) att[i] = e[i] / ssum;
}

// ---------------- W -> fp16, transposed for MFMA B-fragments ----------------
__global__ __launch_bounds__(256) void k_wcvt(const float* __restrict__ W1, const float* __restrict__ W2,
                                              f16* __restrict__ W1T, f16* __restrict__ W2T) {
    int t = blockIdx.x * 256 + threadIdx.x;
    if (t < DIM * HID) {
        int k = t >> 8, j = t & 255;
        W1T[(size_t)j * DIM + k] = (f16)W1[(size_t)k * HID + j];
        int j2 = t >> 7, i = t & 127;
        W2T[(size_t)i * HID + j2] = (f16)W2[(size_t)j2 * DIM + i];
    }
}

// ---------------- propagation: g_out[v] = (sum of g_in[u]) / deg[v], fp8 h ----------------
// QUARTER-WAVE (16 lanes) per node; row = 16 x uint2 = 128 B = one full cache line.
// fp32 accumulate; unroll 4 with edge-index prefetch. At the ~6.3 TB/s random-gather ceiling.
__device__ __forceinline__ void acc8f8(float* f, uint2 h) {
    f32x2 p0 = __builtin_amdgcn_cvt_pk_f32_fp8(h.x, false);
    f32x2 p1 = __builtin_amdgcn_cvt_pk_f32_fp8(h.x, true);
    f32x2 p2 = __builtin_amdgcn_cvt_pk_f32_fp8(h.y, false);
    f32x2 p3 = __builtin_amdgcn_cvt_pk_f32_fp8(h.y, true);
    f[0] += p0.x; f[1] += p0.y; f[2] += p1.x; f[3] += p1.y;
    f[4] += p2.x; f[5] += p2.y; f[6] += p3.x; f[7] += p3.y;
}

__global__ __launch_bounds__(256, 8) void k_prop(const uint2* __restrict__ hin, uint2* __restrict__ hout,
                                                 const int* __restrict__ offs, const unsigned* __restrict__ cedge,
                                                 const float* __restrict__ invdeg, int n) {
    int v = blockIdx.x * 16 + (threadIdx.x >> 4);
    if (v >= n) return;
    int lane = threadIdx.x & 15;
    int b = offs[v], e = offs[v + 1];
    float f[8], g[8];
#pragma unroll
    for (int k = 0; k < 8; ++k) { f[k] = 0.f; g[k] = 0.f; }
    const uint2* hb = hin + lane;   // row s = + s*16 (16 uint2 per row, 128 B)
    int m4 = (e - b) >> 2;
    int i = b;
    if (m4 > 0) {
        unsigned e0 = cedge[i], e1 = cedge[i + 1], e2 = cedge[i + 2], e3 = cedge[i + 3];
        for (int t = 0; t < m4; ++t) {
            uint2 h0 = hb[(size_t)e0 * 16];
            uint2 h1 = hb[(size_t)e1 * 16];
            uint2 h2 = hb[(size_t)e2 * 16];
            uint2 h3 = hb[(size_t)e3 * 16];
            i += 4;
            if (t + 1 < m4) {   // prefetch next group's indices while gathers are in flight
                e0 = cedge[i]; e1 = cedge[i + 1]; e2 = cedge[i + 2]; e3 = cedge[i + 3];
            }
            acc8f8(f, h0); acc8f8(g, h1); acc8f8(f, h2); acc8f8(g, h3);
        }
    }
    for (; i < e; ++i) {
        uint2 h0 = hb[(size_t)cedge[i] * 16];
        acc8f8(f, h0);
    }
    float idv = invdeg[v];
    uint2 ov;
    ov.x = fp8pk4((f[0] + g[0]) * idv, (f[1] + g[1]) * idv, (f[2] + g[2]) * idv, (f[3] + g[3]) * idv);
    ov.y = fp8pk4((f[4] + g[4]) * idv, (f[5] + g[5]) * idv, (f[6] + g[6]) * idv, (f[7] + g[7]) * idv);
    hout[(size_t)v * 16 + lane] = ov;
}

// ---------------- FFN via MFMA: gelu((sqdeg * Σ att_k S_k)@W1+b1)@W2+b2, fp16 out ----------------
#define SA_LD 136   // 64x136 fp16: 272B row stride (17x16B) -> aligned, 2-way bank alias (free)
#define SH_LD 264   // 64x264 fp16: 528B row stride (33x16B) -> aligned
__global__ __launch_bounds__(256, 3) void k_ffn_mfma(const unsigned char* __restrict__ S0,
                                                     const unsigned char* __restrict__ S1,
                                                     const unsigned char* __restrict__ S2,
                                                     const unsigned char* __restrict__ S3,
                                                     const float* __restrict__ attv, const float* __restrict__ sqdeg,
                                                     const f16* __restrict__ W1T, const float* __restrict__ b1,
                                                     const f16* __restrict__ W2T, const float* __restrict__ b2,
                                                     __half* __restrict__ outb, int n) {
    __shared__ f16 sA[64 * SA_LD];
    __shared__ f16 sH[64 * SH_LD];
    int tid = threadIdx.x;
    int wid = tid >> 6;
    int lane = tid & 63;
    int row16 = lane & 15;
    int kgrp = lane >> 4;     // 0..3
    int r0 = blockIdx.x * 64;
    float a0 = attv[0], a1 = attv[1], a2 = attv[2], a3 = attv[3];

    // stage sA: row = sqdeg[row] * (a0*S0 + a1*S1 + a2*S2 + a3*S3), fp8 -> fp16
    const uint2* p0 = (const uint2*)S0;
    const uint2* p1 = (const uint2*)S1;
    const uint2* p2 = (const uint2*)S2;
    const uint2* p3 = (const uint2*)S3;
    for (int idx = tid; idx < 64 * 16; idx += 256) {
        int r = idx >> 4;
        int ch = idx & 15;                 // 8-B chunk (8 fp8 values)
        int row = r0 + r; row = (row < n) ? row : (n - 1);
        float sd = sqdeg[row];
        float w0 = a0 * sd, w1 = a1 * sd, w2 = a2 * sd, w3 = a3 * sd;
        size_t u = (size_t)row * 16 + ch;
        uint2 x0 = p0[u], x1 = p1[u], x2 = p2[u], x3 = p3[u];
        float rv[8];
#pragma unroll
        for (int half = 0; half < 2; ++half) {
            unsigned q0 = half ? x0.y : x0.x, q1 = half ? x1.y : x1.x;
            unsigned q2 = half ? x2.y : x2.x, q3 = half ? x3.y : x3.x;
            f32x2 d0l = __builtin_amdgcn_cvt_pk_f32_fp8(q0, false);
            f32x2 d0h = __builtin_amdgcn_cvt_pk_f32_fp8(q0, true);
            f32x2 d1l = __builtin_amdgcn_cvt_pk_f32_fp8(q1, false);
            f32x2 d1h = __builtin_amdgcn_cvt_pk_f32_fp8(q1, true);
            f32x2 d2l = __builtin_amdgcn_cvt_pk_f32_fp8(q2, false);
            f32x2 d2h = __builtin_amdgcn_cvt_pk_f32_fp8(q2, true);
            f32x2 d3l = __builtin_amdgcn_cvt_pk_f32_fp8(q3, false);
            f32x2 d3h = __builtin_amdgcn_cvt_pk_f32_fp8(q3, true);
            rv[half * 4 + 0] = w0 * d0l.x + w1 * d1l.x + w2 * d2l.x + w3 * d3l.x;
            rv[half * 4 + 1] = w0 * d0l.y + w1 * d1l.y + w2 * d2l.y + w3 * d3l.y;
            rv[half * 4 + 2] = w0 * d0h.x + w1 * d1h.x + w2 * d2h.x + w3 * d3h.x;
            rv[half * 4 + 3] = w0 * d0h.y + w1 * d1h.y + w2 * d2h.y + w3 * d3h.y;
        }
        *(uint4*)(&sA[r * SA_LD + ch * 8]) = make_uint4(f2h2(rv[0], rv[1]), f2h2(rv[2], rv[3]),
                                                        f2h2(rv[4], rv[5]), f2h2(rv[6], rv[7]));
    }
    __syncthreads();

    // ---- GEMM1: sH[0:64][wid*64 : wid*64+64] = gelu(sA @ W1 + b1) ----
    {
        float bias1[4];
#pragma unroll
        for (int nt = 0; nt < 4; ++nt) bias1[nt] = b1[wid * 64 + nt * 16 + row16];
        f32x4 c1[4][4];
#pragma unroll
        for (int mt = 0; mt < 4; ++mt)
#pragma unroll
            for (int nt = 0; nt < 4; ++nt) c1[mt][nt] = (f32x4){0.f, 0.f, 0.f, 0.f};
        for (int ks = 0; ks < 4; ++ks) {   // K = 128 = 4 x 32
            f16x8 a[4], b[4];
#pragma unroll
            for (int mt = 0; mt < 4; ++mt)
                a[mt] = *(const f16x8*)(&sA[(mt * 16 + row16) * SA_LD + ks * 32 + kgrp * 8]);
#pragma unroll
            for (int nt = 0; nt < 4; ++nt)
                b[nt] = *(const f16x8*)(W1T + (size_t)(wid * 64 + nt * 16 + row16) * DIM + ks * 32 + kgrp * 8);
#pragma unroll
            for (int mt = 0; mt < 4; ++mt)
#pragma unroll
                for (int nt = 0; nt < 4; ++nt)
                    c1[mt][nt] = __builtin_amdgcn_mfma_f32_16x16x32_f16(a[mt], b[nt], c1[mt][nt], 0, 0, 0);
        }
#pragma unroll
        for (int mt = 0; mt < 4; ++mt)
#pragma unroll
            for (int nt = 0; nt < 4; ++nt) {
                int srow = mt * 16 + kgrp * 4;
                int scol = wid * 64 + nt * 16 + row16;
#pragma unroll
                for (int r = 0; r < 4; ++r) {
                    float v = c1[mt][nt][r] + bias1[nt];
                    sH[(srow + r) * SH_LD + scol] = (f16)gelu_exact(v);
                }
            }
    }
    __syncthreads();

    // ---- GEMM2: out[0:64][wid*32 : wid*32+32] = sH @ W2 + b2 (fp16 out) ----
    {
        float bias2[2];
#pragma unroll
        for (int nt = 0; nt < 2; ++nt) bias2[nt] = b2[wid * 32 + nt * 16 + row16];
        f32x4 c2[4][2];
#pragma unroll
        for (int mt = 0; mt < 4; ++mt)
#pragma unroll
            for (int nt = 0; nt < 2; ++nt) c2[mt][nt] = (f32x4){0.f, 0.f, 0.f, 0.f};
        for (int ks = 0; ks < 8; ++ks) {   // K = 256 = 8 x 32
            f16x8 a[4], b[2];
#pragma unroll
            for (int mt = 0; mt < 4; ++mt)
                a[mt] = *(const f16x8*)(&sH[(mt * 16 + row16) * SH_LD + ks * 32 + kgrp * 8]);
#pragma unroll
            for (int nt = 0; nt < 2; ++nt)
                b[nt] = *(const f16x8*)(W2T + (size_t)(wid * 32 + nt * 16 + row16) * HID + ks * 32 + kgrp * 8);
#pragma unroll
            for (int mt = 0; mt < 4; ++mt)
#pragma unroll
                for (int nt = 0; nt < 2; ++nt)
                    c2[mt][nt] = __builtin_amdgcn_mfma_f32_16x16x32_f16(a[mt], b[nt], c2[mt][nt], 0, 0, 0);
        }
#pragma unroll
        for (int mt = 0; mt < 4; ++mt)
#pragma unroll
            for (int nt = 0; nt < 2; ++nt) {
                int col = wid * 32 + nt * 16 + row16;
#pragma unroll
                for (int r = 0; r < 4; ++r) {
                    int row = r0 + mt * 16 + kgrp * 4 + r;
                    if (row < n) outb[(size_t)row * DIM + col] = (__half)(c2[mt][nt][r] + bias2[nt]);
                }
            }
    }
}

// ---------------- inverse bundle (R^T @ H), H fp16, + concat output ----------------
__global__ __launch_bounds__(256) void k_inv_out(const float* __restrict__ x, const float* __restrict__ nr,
                                                 const __half* __restrict__ hf, float* __restrict__ out, int n) {
    int t = blockIdx.x * 256 + threadIdx.x;
    if (t >= n * 8) return;
    int node = t >> 3, b = t & 7;
    const float4* Xin = (const float4*)(x + (size_t)node * DIM + b * 16);
    float4* Ox = (float4*)(out + (size_t)node * 2 * DIM + b * 16);
#pragma unroll
    for (int k = 0; k < 4; ++k) Ox[k] = Xin[k];
    const uint4* Hp = (const uint4*)(hf + (size_t)node * DIM + b * 16);
    uint4 hlo = Hp[0], hhi = Hp[1];
    float4 H[4];
    {
        float2 u0 = h2f2(hlo.x), u1 = h2f2(hlo.y);
        H[0] = make_float4(u0.x, u0.y, u1.x, u1.y);
        float2 u2 = h2f2(hlo.z), u3 = h2f2(hlo.w);
        H[1] = make_float4(u2.x, u2.y, u3.x, u3.y);
        float2 u4 = h2f2(hhi.x), u5 = h2f2(hhi.y);
        H[2] = make_float4(u4.x, u4.y, u5.x, u5.y);
        float2 u6 = h2f2(hhi.z), u7 = h2f2(hhi.w);
        H[3] = make_float4(u6.x, u6.y, u7.x, u7.y);
    }
    const float4* Rp = (const float4*)(nr + (size_t)node * DIM + b * 16);
    float4 R[4];
#pragma unroll
    for (int k = 0; k < 4; ++k) R[k] = Rp[k];
    float4* Om = (float4*)(out + (size_t)node * 2 * DIM + DIM + b * 16);
    {
        float4 O;
        O.x = fmaf(R[0].x, H[0].x, fmaf(R[1].x, H[1].x, fmaf(R[2].x, H[2].x, R[3].x * H[3].x)));
        O.y = fmaf(R[0].x, H[0].y, fmaf(R[1].x, H[1].y, fmaf(R[2].x, H[2].y, R[3].x * H[3].y)));
        O.z = fmaf(R[0].x, H[0].z, fmaf(R[1].x, H[1].z, fmaf(R[2].x, H[2].z, R[3].x * H[3].z)));
        O.w = fmaf(R[0].x, H[0].w, fmaf(R[1].x, H[1].w, fmaf(R[2].x, H[2].w, R[3].x * H[3].w)));
        Om[0] = O;
    }
    {
        float4 O;
        O.x = fmaf(R[0].y, H[0].x, fmaf(R[1].y, H[1].x, fmaf(R[2].y, H[2].x, R[3].y * H[3].x)));
        O.y = fmaf(R[0].y, H[0].y, fmaf(R[1].y, H[1].y, fmaf(R[2].y, H[2].y, R[3].y * H[3].y)));
        O.z = fmaf(R[0].y, H[0].z, fmaf(R[1].y, H[1].z, fmaf(R[2].y, H[2].z, R[3].y * H[3].z)));
        O.w = fmaf(R[0].y, H[0].w, fmaf(R[1].y, H[1].w, fmaf(R[2].y, H[2].w, R[3].y * H[3].w)));
        Om[1] = O;
    }
    {
        float4 O;
        O.x = fmaf(R[0].z, H[0].x, fmaf(R[1].z, H[1].x, fmaf(R[2].z, H[2].x, R[3].z * H[3].x)));
        O.y = fmaf(R[0].z, H[0].y, fmaf(R[1].z, H[1].y, fmaf(R[2].z, H[2].y, R[3].z * H[3].y)));
        O.z = fmaf(R[0].z, H[0].z, fmaf(R[1].z, H[1].z, fmaf(R[2].z, H[2].z, R[3].z * H[3].z)));
        O.w = fmaf(R[0].z, H[0].w, fmaf(R[1].z, H[1].w, fmaf(R[2].z, H[2].w, R[3].z * H[3].w)));
        Om[2] = O;
    }
    {
        float4 O;
        O.x = fmaf(R[0].w, H[0].x, fmaf(R[1].w, H[1].x, fmaf(R[2].w, H[2].x, R[3].w * H[3].x)));
        O.y = fmaf(R[0].w, H[0].y, fmaf(R[1].w, H[1].y, fmaf(R[2].w, H[2].y, R[3].w * H[3].y)));
        O.z = fmaf(R[0].w, H[0].z, fmaf(R[1].w, H[1].z, fmaf(R[2].w, H[2].z, R[3].w * H[3].z)));
        O.w = fmaf(R[0].w, H[0].w, fmaf(R[1].w, H[1].w, fmaf(R[2].w, H[2].w, R[3].w * H[3].w)));
        Om[3] = O;
    }
}

extern "C" void kernel_launch(void* const* d_in, const int* in_sizes, int n_in,
                              void* d_out, int out_size, void* d_ws, size_t ws_size,
                              hipStream_t stream) {
    const float* x         = (const float*)d_in[0];
    const float* nrep      = (const float*)d_in[1];
    const int*   src       = (const int*)d_in[2];
    const int*   dst       = (const int*)d_in[3];
    const float* attention = (const float*)d_in[4];
    const float* W1        = (const float*)d_in[5];
    const float* b1        = (const float*)d_in[6];
    const float* W2        = (const float*)d_in[7];
    const float* b2        = (const float*)d_in[8];
    float* out = (float*)d_out;

    int n = in_sizes[0] / DIM;
    int E = in_sizes[2];

    char* w = (char*)d_ws;
    size_t off = 0;
    auto alloc = [&](size_t bytes) -> char* {
        char* p = w + off;
        off = (off + bytes + 255) & ~(size_t)255;
        return p;
    };
    size_t hbytes = (size_t)n * DIM;       // fp8 h buffer (1 B/elem)
    int*      deg    = (int*)alloc((size_t)n * 4);
    int*      cursor = (int*)alloc((size_t)n * 4);
    int*      offs   = (int*)alloc((size_t)(n + 1) * 4);
    int       nb     = (n + 1023) / 1024;
    int*      bsum   = (int*)alloc((size_t)nb * 4);
    float*    attbuf = (float*)alloc(8 * 4);
    float*    invdeg = (float*)alloc((size_t)n * 4);
    float*    sqdeg  = (float*)alloc((size_t)n * 4);
    unsigned* cedge  = (unsigned*)alloc((size_t)E * 4);
    char*     region = alloc(hbytes * 2);          // B0 + T1 (fp8); ffin (fp16) overlays both
    unsigned char* B0 = (unsigned char*)region;
    unsigned char* T1 = (unsigned char*)(region + hbytes);
    __half*   ffin   = (__half*)region;            // n*DIM*2 bytes = hbytes*2
    unsigned char* S[4];
    for (int k = 0; k < 4; ++k) S[k] = (unsigned char*)alloc(hbytes);
    f16*      W1T    = (f16*)alloc((size_t)DIM * HID * 2);
    f16*      W2T    = (f16*)alloc((size_t)DIM * HID * 2);

    hipMemsetAsync(deg, 0, (size_t)n * 4, stream);
    hipMemsetAsync(cursor, 0, (size_t)n * 4, stream);

    k_deg<<<(E + 255) / 256, 256, 0, stream>>>(src, deg, E);
    k_dscale<<<(n + 255) / 256, 256, 0, stream>>>(deg, invdeg, sqdeg, n);
    k_scan_part<<<nb, 256, 0, stream>>>(deg, bsum, n);
    k_scan_bsum<<<1, 64, 0, stream>>>(bsum, nb, offs, n, E);
    k_scan_off<<<nb, 256, 0, stream>>>(deg, bsum, offs, n);
    {
        int nchunks = (E + FCHUNK - 1) / FCHUNK;
        k_fill<<<nchunks * 8, 256, 0, stream>>>(src, dst, offs, cursor, cedge, E, n);
    }
    k_bundle<<<(n * 8 + 255) / 256, 256, 0, stream>>>(x, nrep, deg, B0, n);
    k_softmax<<<1, 64, 0, stream>>>(attention, attbuf);
    k_wcvt<<<(DIM * HID + 255) / 256, 256, 0, stream>>>(W1, W2, W1T, W2T);

    // snapshots at t = 1,2,5,20 land in S0..S3 by buffer scheduling (never overwritten after)
    unsigned char* cur = B0;
    for (int t = 1; t <= 20; ++t) {   // t=21 in reference is dead code
        int snap = (t == 1) ? 0 : (t == 2) ? 1 : (t == 5) ? 2 : (t == 20) ? 3 : -1;
        unsigned char* nxt = (snap >= 0) ? S[snap] : ((cur == B0) ? T1 : B0);
        k_prop<<<(n + 15) / 16, 256, 0, stream>>>((const uint2*)cur, (uint2*)nxt, offs, cedge, invdeg, n);
        cur = nxt;
    }
    k_ffn_mfma<<<(n + 63) / 64, 256, 0, stream>>>(S[0], S[1], S[2], S[3], attbuf, sqdeg,
                                                  W1T, b1, W2T, b2, ffin, n);
    k_inv_out<<<(n * 8 + 255) / 256, 256, 0, stream>>>(x, nrep, ffin, out, n);
}